// Round 7
// baseline (333.746 us; speedup 1.0000x reference)
//
#include <hip/hip_runtime.h>
#include <math.h>

#define N     12
#define HID   64
#define STP   68     // padded row stride for bufL/bufR (272 B rows, 16B-aligned)
#define RPW   3      // rows per wave (4 waves per graph)
#define SLOPE 0.2f
#define ALPHA 0.1f

typedef float v2f __attribute__((ext_vector_type(2)));
typedef float v4f __attribute__((ext_vector_type(4)));

// flat output offsets (float32 elements)
#define OUT0 0          // batch[:,:,:4]
#define OUT1 196608     // batch[:,:,4:5]
#define OUT2 245760     // logits
#define OUT3 442368     // values
#define OUT4 491520     // latent

// ws layout: 7 transposed 64x64 matrices (wsT[m*4096 + t*64 + c] = W[c*64+t]),
// then labT[c*64+h] = lab_w[h*4+c] (256 floats)
__global__ void prep_kernel(const float* __restrict__ enc_w2,
                            const float* __restrict__ g2_wl, const float* __restrict__ g2_wr,
                            const float* __restrict__ g3_wl, const float* __restrict__ g3_wr,
                            const float* __restrict__ g4_wl, const float* __restrict__ g4_wr,
                            const float* __restrict__ lab_w,
                            float* __restrict__ ws) {
    int t = threadIdx.x;
    if (blockIdx.x == 448) {
        #pragma unroll
        for (int c = 0; c < 4; c++) ws[7*4096 + c*64 + t] = lab_w[t*4 + c];
        return;
    }
    int m = blockIdx.x >> 6, c = blockIdx.x & 63;
    const float* src;
    switch (m) {
        case 0: src = enc_w2; break;
        case 1: src = g2_wl;  break;
        case 2: src = g2_wr;  break;
        case 3: src = g3_wl;  break;
        case 4: src = g3_wr;  break;
        case 5: src = g4_wl;  break;
        default: src = g4_wr; break;
    }
    ws[m*4096 + t*64 + c] = src[c*64 + t];
}

// One graph per 256-thread block, 4 waves; wave w owns rows 3w..3w+2.
// R6 lesson: with all waves resident, wall time = per-wave serial path ->
// split the graph across 4 waves to cut the path ~4x (score: 1 slot/wave
// instead of 3; stage/enc/aggregate: 3 rows instead of 12).
// R3/R4 lesson: keep the 16-iter K-loops ROLLED (full unroll spills).
// R5 lesson: padded stride, not rotate swizzle (addressing VALU).
template<bool TW>
__global__ __launch_bounds__(256, 4) void gae_kernel(
    const float* __restrict__ batch,
    const float* __restrict__ enc_w1, const float* __restrict__ enc_b1,
    const float* __restrict__ enc_w2, const float* __restrict__ enc_b2,
    const float* __restrict__ enc_w3, const float* __restrict__ enc_b3,
    const float* __restrict__ g1_wl, const float* __restrict__ g1_wr,
    const float* __restrict__ g1_att, const float* __restrict__ g1_b,
    const float* __restrict__ g2_wl, const float* __restrict__ g2_wr,
    const float* __restrict__ g2_att, const float* __restrict__ g2_b,
    const float* __restrict__ g3_wl, const float* __restrict__ g3_wr,
    const float* __restrict__ g3_att, const float* __restrict__ g3_b,
    const float* __restrict__ g4_wl, const float* __restrict__ g4_wr,
    const float* __restrict__ g4_att, const float* __restrict__ g4_b,
    const float* __restrict__ lab_w, const float* __restrict__ lab_b,
    const float* __restrict__ val_w, const float* __restrict__ val_b,
    const float* __restrict__ skip_w, const float* __restrict__ skip_b,
    const float* __restrict__ wsT,
    float* __restrict__ out)
{
    const int b   = blockIdx.x;
    const int tid = threadIdx.x;
    const int w   = tid >> 6;     // wave id 0..3
    const int t   = tid & 63;     // lane
    const int r0  = w * RPW;      // this wave's rows: r0..r0+2

    __shared__ __align__(16) float lds[2*N*STP + N*HID + 144];
    float* bufL = lds;                    // stride STP
    float* bufR = lds + N*STP;            // stride STP
    float* xB   = lds + 2*N*STP;          // stride HID (x2; broadcast-read only)
    float* pool = lds + 2*N*STP + N*HID;  // batch(60) -> lat(36) -> e(144)

    const v2f z2 = {0.f, 0.f};
    const v4f z4 = {0.f, 0.f, 0.f, 0.f};
    const v4f s4 = {SLOPE, SLOPE, SLOPE, SLOPE};

    // this wave's score pair: p = 64*w + t  (waves 0,1 full; wave 2 lanes<16; wave 3 none)
    const int  praw   = 64*w + t;
    const bool pvalid = praw < 144;
    const int  pw     = pvalid ? praw : 143;
    const int  iw     = pw / N, jw = pw - iw*N;

    // ---- stage batch into pool, emit passthrough outputs 0/1 ----
    if (tid < N*5) {
        float v = batch[b*(N*5) + tid];
        pool[tid] = v;
        int i = tid / 5, f = tid - i*5;
        if (f < 4) out[OUT0 + (size_t)b*(N*4) + i*4 + f] = v;
        else       out[OUT1 + (size_t)b*N + i] = v;
    }
    __syncthreads();

    // ---- encoder layer 1 (own rows) ----
    {
        float acc[RPW];
        float bias = enc_b1[t];
        #pragma unroll
        for (int ri=0;ri<RPW;ri++) acc[ri] = bias;
        #pragma unroll
        for (int f=0; f<5; f++) {
            float wv = enc_w1[f*HID + t];
            #pragma unroll
            for (int ri=0;ri<RPW;ri++) acc[ri] = fmaf(pool[(r0+ri)*5+f], wv, acc[ri]);
        }
        #pragma unroll
        for (int ri=0;ri<RPW;ri++) bufL[(r0+ri)*STP + t] = fmaxf(acc[ri], 0.f);
    }
    __syncthreads();

    // ---- encoder layer 2 (own rows; K-loop ROLLED) ----
    {
        v2f acc[RPW];
        #pragma unroll
        for (int ri=0;ri<RPW;ri++) acc[ri] = z2;
        const float* w2p = TW ? (wsT + 0*4096 + t*HID) : nullptr;
        const float* x0p = &bufL[(r0+0)*STP];
        const float* x1p = &bufL[(r0+1)*STP];
        const float* x2p = &bufL[(r0+2)*STP];
        for (int c=0;c<HID;c+=4) {
            v2f w01, w23;
            if (TW) {
                v4f w4 = *reinterpret_cast<const v4f*>(&w2p[c]);
                w01 = w4.xy; w23 = w4.zw;
            } else {
                w01 = (v2f){enc_w2[(c+0)*HID+t], enc_w2[(c+1)*HID+t]};
                w23 = (v2f){enc_w2[(c+2)*HID+t], enc_w2[(c+3)*HID+t]};
            }
            v4f xv0 = *reinterpret_cast<const v4f*>(x0p + c);
            v4f xv1 = *reinterpret_cast<const v4f*>(x1p + c);
            v4f xv2 = *reinterpret_cast<const v4f*>(x2p + c);
            acc[0] = __builtin_elementwise_fma(xv0.xy, w01, acc[0]);
            acc[0] = __builtin_elementwise_fma(xv0.zw, w23, acc[0]);
            acc[1] = __builtin_elementwise_fma(xv1.xy, w01, acc[1]);
            acc[1] = __builtin_elementwise_fma(xv1.zw, w23, acc[1]);
            acc[2] = __builtin_elementwise_fma(xv2.xy, w01, acc[2]);
            acc[2] = __builtin_elementwise_fma(xv2.zw, w23, acc[2]);
        }
        float bias = enc_b2[t];
        #pragma unroll
        for (int ri=0;ri<RPW;ri++)
            bufR[(r0+ri)*STP + t] = fmaxf(bias + acc[ri].x + acc[ri].y, 0.f);
    }
    __syncthreads();

    // ---- latent = h2 @ W3 + b3 (36 outputs; lanes tid<36) -> pool[0..35] ----
    if (tid < N*3) {
        int i = tid / 3, c = tid - i*3;
        float acc = enc_b3[c];
        for (int k=0;k<HID;k+=4) {
            v4f xv = *reinterpret_cast<const v4f*>(&bufR[i*STP + k]);
            acc = fmaf(xv.x, enc_w3[(k+0)*3+c], acc);
            acc = fmaf(xv.y, enc_w3[(k+1)*3+c], acc);
            acc = fmaf(xv.z, enc_w3[(k+2)*3+c], acc);
            acc = fmaf(xv.w, enc_w3[(k+3)*3+c], acc);
        }
        pool[tid] = acc;
        out[OUT4 + (size_t)b*(N*3) + tid] = acc;
    }
    __syncthreads();

    // ---- skip connection for own rows -> registers ----
    float skipv[RPW];
    {
        float w0 = skip_w[t], w1 = skip_w[HID+t], w2 = skip_w[2*HID+t];
        float bias = skip_b[t];
        #pragma unroll
        for (int ri=0;ri<RPW;ri++) {
            int i = r0 + ri;
            float v = bias;
            v = fmaf(pool[i*3+0], w0, v);
            v = fmaf(pool[i*3+1], w1, v);
            v = fmaf(pool[i*3+2], w2, v);
            skipv[ri] = v;
        }
    }

    // ---- Gabriel adjacency via per-wave ballots (each wave computes all 3) ----
    auto gab = [&](int i, int j)->bool {
        if (i == j) return false;
        float pix = pool[i*3], piy = pool[i*3+1];
        float pjx = pool[j*3], pjy = pool[j*3+1];
        float mx = (pix + pjx) * 0.5f, my = (piy + pjy) * 0.5f;
        float dx = pix - pjx, dy = piy - pjy;
        float r2 = (dx*dx + dy*dy) * 0.25f;
        bool g = true;
        #pragma unroll
        for (int k=0;k<N;k++) {
            float ex = pool[k*3] - mx, ey = pool[k*3+1] - my;
            bool ok = (k == i) || (k == j) || (ex*ex + ey*ey > r2);
            g = g && ok;
        }
        return g;
    };
    const int bi0 = t / N,          bj0 = t - bi0*N;          // pairs 0..63
    const int bp1 = t + 64;
    const int bi1 = bp1 / N,        bj1 = bp1 - bi1*N;        // pairs 64..127
    const int bp2 = (t < 16) ? (t + 128) : 143;
    const int bi2 = bp2 / N,        bj2 = bp2 - bi2*N;        // pairs 128..143
    unsigned long long gb0 = __ballot(gab(bi0, bj0));
    unsigned long long gb1 = __ballot(gab(bi1, bj1));
    unsigned long long gb2 = __ballot((t < 16) && gab(bi2, bj2));
    auto gbit = [&](int p)->int {
        unsigned long long m = (p < 64) ? gb0 : ((p < 128) ? gb1 : gb2);
        return (int)((m >> (p & 63)) & 1ull);
    };
    const int adjw = gbit(pw) | gbit(jw*N+iw) | (iw == jw);

    // ---- GATv2 core: score (1 slot/wave) -> softmax -> aggregate (own rows) ----
    auto gat_core = [&](const float* __restrict__ att, const float* __restrict__ gb,
                        float* __restrict__ xout, int strideOut, int useSkip) {
        __syncthreads();   // staged xl/xr visible to all waves
        if (w < 3) {
            const float* Lj = &bufL[jw*STP];
            const float* Ri = &bufR[iw*STP];
            v4f aA = z4;
            for (int h=0; h<HID; h+=4) {
                v4f a4 = *reinterpret_cast<const v4f*>(&att[h]);   // uniform -> scalar load
                v4f xl = *reinterpret_cast<const v4f*>(Lj + h);
                v4f xr = *reinterpret_cast<const v4f*>(Ri + h);
                v4f s = xl + xr;
                v4f l = __builtin_elementwise_fma(s4, __builtin_elementwise_min(s, z4),
                                                 __builtin_elementwise_max(s, z4));
                aA = __builtin_elementwise_fma(a4, l, aA);
            }
            float e = (aA.x + aA.y) + (aA.z + aA.w);
            if (pvalid) pool[pw] = adjw ? e : -1e9f;
        }
        __syncthreads();
        if (tid < N) {   // row softmax (wave 0, 12 lanes)
            float m = -2e9f;
            #pragma unroll
            for (int j=0;j<N;j++) m = fmaxf(m, pool[tid*N+j]);
            float tmp[N]; float sum = 0.f;
            #pragma unroll
            for (int j=0;j<N;j++) { float v = __expf(pool[tid*N+j] - m); tmp[j] = v; sum += v; }
            float inv = 1.0f / sum;
            #pragma unroll
            for (int j=0;j<N;j++) pool[tid*N+j] = tmp[j] * inv;
        }
        __syncthreads();
        {
            float xj[N];
            #pragma unroll
            for (int j=0;j<N;j++) xj[j] = bufL[j*STP + t];   // base t, imm 272j
            v4f X0 = {xj[0], xj[1], xj[2],  xj[3]};
            v4f X1 = {xj[4], xj[5], xj[6],  xj[7]};
            v4f X2 = {xj[8], xj[9], xj[10], xj[11]};
            float bias = gb[t];
            #pragma unroll
            for (int ri=0;ri<RPW;ri++) {
                int i = r0 + ri;
                const v4f* ep = reinterpret_cast<const v4f*>(&pool[i*N]);
                v4f acc = __builtin_elementwise_fma(ep[0], X0,
                          __builtin_elementwise_fma(ep[1], X1, ep[2]*X2));
                float r = bias + ((acc.x + acc.y) + (acc.z + acc.w));
                if (useSkip) r = fmaf(ALPHA, skipv[ri], r);
                xout[i*strideOut + t] = fmaxf(r, 0.f);
            }
        }
        __syncthreads();
    };

    // ---- stage xl/xr for own rows (K-loop ROLLED) ----
    auto stage = [&](const float* __restrict__ xin, int strideIn,
                     const float* __restrict__ wlT, const float* __restrict__ wrT,
                     const float* __restrict__ wl, const float* __restrict__ wr) {
        v2f al[RPW], ar[RPW];
        #pragma unroll
        for (int ri=0;ri<RPW;ri++) { al[ri] = z2; ar[ri] = z2; }
        const float* x0p = &xin[(r0+0)*strideIn];
        const float* x1p = &xin[(r0+1)*strideIn];
        const float* x2p = &xin[(r0+2)*strideIn];
        for (int c=0;c<HID;c+=4) {
            v2f wl01, wl23, wr01, wr23;
            if (TW) {
                v4f w4 = *reinterpret_cast<const v4f*>(&wlT[c]);
                v4f u4 = *reinterpret_cast<const v4f*>(&wrT[c]);
                wl01 = w4.xy; wl23 = w4.zw;
                wr01 = u4.xy; wr23 = u4.zw;
            } else {
                wl01 = (v2f){wl[(c+0)*HID+t], wl[(c+1)*HID+t]};
                wl23 = (v2f){wl[(c+2)*HID+t], wl[(c+3)*HID+t]};
                wr01 = (v2f){wr[(c+0)*HID+t], wr[(c+1)*HID+t]};
                wr23 = (v2f){wr[(c+2)*HID+t], wr[(c+3)*HID+t]};
            }
            v4f xv0 = *reinterpret_cast<const v4f*>(x0p + c);
            v4f xv1 = *reinterpret_cast<const v4f*>(x1p + c);
            v4f xv2 = *reinterpret_cast<const v4f*>(x2p + c);
            al[0] = __builtin_elementwise_fma(xv0.xy, wl01, al[0]);
            al[0] = __builtin_elementwise_fma(xv0.zw, wl23, al[0]);
            ar[0] = __builtin_elementwise_fma(xv0.xy, wr01, ar[0]);
            ar[0] = __builtin_elementwise_fma(xv0.zw, wr23, ar[0]);
            al[1] = __builtin_elementwise_fma(xv1.xy, wl01, al[1]);
            al[1] = __builtin_elementwise_fma(xv1.zw, wl23, al[1]);
            ar[1] = __builtin_elementwise_fma(xv1.xy, wr01, ar[1]);
            ar[1] = __builtin_elementwise_fma(xv1.zw, wr23, ar[1]);
            al[2] = __builtin_elementwise_fma(xv2.xy, wl01, al[2]);
            al[2] = __builtin_elementwise_fma(xv2.zw, wl23, al[2]);
            ar[2] = __builtin_elementwise_fma(xv2.xy, wr01, ar[2]);
            ar[2] = __builtin_elementwise_fma(xv2.zw, wr23, ar[2]);
        }
        #pragma unroll
        for (int ri=0;ri<RPW;ri++) {
            bufL[(r0+ri)*STP + t] = al[ri].x + al[ri].y;
            bufR[(r0+ri)*STP + t] = ar[ri].x + ar[ri].y;
        }
    };

    // ---- GAT layer 1 (cin = 1; x0 = lat[:,2] from pool; own rows) ----
    {
        float wlv = g1_wl[t], wrv = g1_wr[t];
        #pragma unroll
        for (int ri=0;ri<RPW;ri++) {
            int i = r0 + ri;
            float v = pool[i*3+2];
            bufL[i*STP + t] = v * wlv;
            bufR[i*STP + t] = v * wrv;
        }
    }
    gat_core(g1_att, g1_b, bufR, STP, 0);   // x1 -> bufR

    // ---- GAT layer 2 ----
    stage(bufR, STP, TW ? wsT + 1*4096 + t*HID : nullptr,
                     TW ? wsT + 2*4096 + t*HID : nullptr, g2_wl, g2_wr);
    gat_core(g2_att, g2_b, xB, HID, 0);     // x2 -> xB (persists)

    // ---- GAT layer 3 ----
    stage(xB, HID, TW ? wsT + 3*4096 + t*HID : nullptr,
                   TW ? wsT + 4*4096 + t*HID : nullptr, g3_wl, g3_wr);
    gat_core(g3_att, g3_b, bufR, STP, 1);   // x3 -> bufR

    // ---- logits head: x3 @ lab_w + lab_b (tid<48, wave 0) ----
    if (tid < N*4) {
        int i = tid >> 2, c = tid & 3;
        float acc = lab_b[c];
        if (TW) {
            const float* lwT = wsT + 7*4096 + c*HID;
            for (int h=0;h<HID;h+=4) {
                v4f xv = *reinterpret_cast<const v4f*>(&bufR[i*STP + h]);
                v4f w4 = *reinterpret_cast<const v4f*>(&lwT[h]);
                acc = fmaf(xv.x, w4.x, acc);
                acc = fmaf(xv.y, w4.y, acc);
                acc = fmaf(xv.z, w4.z, acc);
                acc = fmaf(xv.w, w4.w, acc);
            }
        } else {
            for (int h=0;h<HID;h+=4) {
                v4f xv = *reinterpret_cast<const v4f*>(&bufR[i*STP + h]);
                acc = fmaf(xv.x, lab_w[(h+0)*4+c], acc);
                acc = fmaf(xv.y, lab_w[(h+1)*4+c], acc);
                acc = fmaf(xv.z, lab_w[(h+2)*4+c], acc);
                acc = fmaf(xv.w, lab_w[(h+3)*4+c], acc);
            }
        }
        out[OUT2 + (size_t)b*(N*4) + tid] = acc;
    }
    __syncthreads();   // head reads bufR (x3) before stage(g4) overwrites it

    // ---- GAT layer 4 ----
    stage(xB, HID, TW ? wsT + 5*4096 + t*HID : nullptr,
                   TW ? wsT + 6*4096 + t*HID : nullptr, g4_wl, g4_wr);
    gat_core(g4_att, g4_b, bufR, STP, 1);   // x4 -> bufR

    // ---- values head (tid<12) ----
    if (tid < N) {
        float acc = val_b[0];
        for (int h=0;h<HID;h+=4) {
            v4f xv = *reinterpret_cast<const v4f*>(&bufR[tid*STP + h]);
            v4f w4 = *reinterpret_cast<const v4f*>(&val_w[h]);
            acc = fmaf(xv.x, w4.x, acc);
            acc = fmaf(xv.y, w4.y, acc);
            acc = fmaf(xv.z, w4.z, acc);
            acc = fmaf(xv.w, w4.w, acc);
        }
        out[OUT3 + (size_t)b*N + tid] = acc;
    }
}

extern "C" void kernel_launch(void* const* d_in, const int* in_sizes, int n_in,
                              void* d_out, int out_size, void* d_ws, size_t ws_size,
                              hipStream_t stream) {
    (void)in_sizes; (void)n_in; (void)out_size;
    const bool useT = (ws_size >= (7*4096 + 256)*sizeof(float));
    if (useT) {
        prep_kernel<<<dim3(449), dim3(64), 0, stream>>>(
            (const float*)d_in[3],
            (const float*)d_in[11], (const float*)d_in[12],
            (const float*)d_in[15], (const float*)d_in[16],
            (const float*)d_in[19], (const float*)d_in[20],
            (const float*)d_in[23],
            (float*)d_ws);
        gae_kernel<true><<<dim3(4096), dim3(256), 0, stream>>>(
            (const float*)d_in[0],
            (const float*)d_in[1],  (const float*)d_in[2],
            (const float*)d_in[3],  (const float*)d_in[4],
            (const float*)d_in[5],  (const float*)d_in[6],
            (const float*)d_in[7],  (const float*)d_in[8],  (const float*)d_in[9],  (const float*)d_in[10],
            (const float*)d_in[11], (const float*)d_in[12], (const float*)d_in[13], (const float*)d_in[14],
            (const float*)d_in[15], (const float*)d_in[16], (const float*)d_in[17], (const float*)d_in[18],
            (const float*)d_in[19], (const float*)d_in[20], (const float*)d_in[21], (const float*)d_in[22],
            (const float*)d_in[23], (const float*)d_in[24],
            (const float*)d_in[25], (const float*)d_in[26],
            (const float*)d_in[27], (const float*)d_in[28],
            (const float*)d_ws,
            (float*)d_out);
    } else {
        gae_kernel<false><<<dim3(4096), dim3(256), 0, stream>>>(
            (const float*)d_in[0],
            (const float*)d_in[1],  (const float*)d_in[2],
            (const float*)d_in[3],  (const float*)d_in[4],
            (const float*)d_in[5],  (const float*)d_in[6],
            (const float*)d_in[7],  (const float*)d_in[8],  (const float*)d_in[9],  (const float*)d_in[10],
            (const float*)d_in[11], (const float*)d_in[12], (const float*)d_in[13], (const float*)d_in[14],
            (const float*)d_in[15], (const float*)d_in[16], (const float*)d_in[17], (const float*)d_in[18],
            (const float*)d_in[19], (const float*)d_in[20], (const float*)d_in[21], (const float*)d_in[22],
            (const float*)d_in[23], (const float*)d_in[24],
            (const float*)d_in[25], (const float*)d_in[26],
            (const float*)d_in[27], (const float*)d_in[28],
            nullptr,
            (float*)d_out);
    }
}

// Round 8
// 182.763 us; speedup vs baseline: 1.8261x; 1.8261x over previous
//
#include <hip/hip_runtime.h>
#include <hip/hip_bf16.h>
#include <math.h>

#define N     12
#define HID   64
#define STP   68     // padded row stride for bufL/bufR (272 B rows, 16B-aligned)
#define SLOPE 0.2f
#define ALPHA 0.1f

typedef float v2f __attribute__((ext_vector_type(2)));
typedef float v4f __attribute__((ext_vector_type(4)));

// flat output offsets (float32 elements)
#define OUT0 0          // batch[:,:,:4]
#define OUT1 196608     // batch[:,:,4:5]
#define OUT2 245760     // logits
#define OUT3 442368     // values
#define OUT4 491520     // latent

// ws layout (floats unless noted):
//   [0,4096)        enc_w2 transposed, fp32  (enc path MUST stay fp32: latent feeds
//                   Gabriel d2>r2 comparisons -> bf16 could flip adjacency bits)
//   [4096, +6*2048) 6 GAT matrices (g2wl,g2wr,g3wl,g3wr,g4wl,g4wr) transposed, BF16
//                   (ushort): w16[mm*4096 + t*64 + c] = bf16(W[c*64+t])
//   [10240, +256)   labT fp32: labT[c*64+h] = lab_w[h*4+c]
__global__ void prep_kernel(const float* __restrict__ enc_w2,
                            const float* __restrict__ g2_wl, const float* __restrict__ g2_wr,
                            const float* __restrict__ g3_wl, const float* __restrict__ g3_wr,
                            const float* __restrict__ g4_wl, const float* __restrict__ g4_wr,
                            const float* __restrict__ lab_w,
                            float* __restrict__ ws) {
    int t = threadIdx.x;
    int bx = blockIdx.x;
    if (bx == 448) {
        #pragma unroll
        for (int c = 0; c < 4; c++) ws[10240 + c*64 + t] = lab_w[t*4 + c];
        return;
    }
    if (bx < 64) {                       // enc_w2 fp32 transpose
        int c = bx;
        ws[t*64 + c] = enc_w2[c*64 + t];
        return;
    }
    int mm = (bx - 64) >> 6, c = bx & 63;
    const float* src;
    switch (mm) {
        case 0: src = g2_wl; break;
        case 1: src = g2_wr; break;
        case 2: src = g3_wl; break;
        case 3: src = g3_wr; break;
        case 4: src = g4_wl; break;
        default: src = g4_wr; break;
    }
    __hip_bfloat16 h = __float2bfloat16(src[c*64 + t]);
    unsigned short* w16 = (unsigned short*)(ws + 4096);
    w16[mm*4096 + t*64 + c] = *(unsigned short*)&h;
}

// One graph per 64-lane wave (R7 lesson: multi-wave blocks convoy on barriers and
// lose independent-graph overlap; single-wave blocks make __syncthreads ~free).
// LDS: bufL(816) + bufR(816) + xB(768) + pool(144) + pairs8(64B) = 10240 B exactly
//   -> 16 blocks/CU.
// R3/R4: keep 16-iter K-loops ROLLED (full unroll spills ~100MB scratch traffic).
// R5:    padded stride, not rotate swizzle.
// R8:    sparse score (Gabriel has <=68 valid directed pairs of 144) + bf16 GAT
//        weights (L1-resident; enc path stays fp32 for adjacency determinism).
template<bool TW>
__global__ __launch_bounds__(64, 3) void gae_kernel(
    const float* __restrict__ batch,
    const float* __restrict__ enc_w1, const float* __restrict__ enc_b1,
    const float* __restrict__ enc_w2, const float* __restrict__ enc_b2,
    const float* __restrict__ enc_w3, const float* __restrict__ enc_b3,
    const float* __restrict__ g1_wl, const float* __restrict__ g1_wr,
    const float* __restrict__ g1_att, const float* __restrict__ g1_b,
    const float* __restrict__ g2_wl, const float* __restrict__ g2_wr,
    const float* __restrict__ g2_att, const float* __restrict__ g2_b,
    const float* __restrict__ g3_wl, const float* __restrict__ g3_wr,
    const float* __restrict__ g3_att, const float* __restrict__ g3_b,
    const float* __restrict__ g4_wl, const float* __restrict__ g4_wr,
    const float* __restrict__ g4_att, const float* __restrict__ g4_b,
    const float* __restrict__ lab_w, const float* __restrict__ lab_b,
    const float* __restrict__ val_w, const float* __restrict__ val_b,
    const float* __restrict__ skip_w, const float* __restrict__ skip_b,
    const float* __restrict__ wsT,
    float* __restrict__ out)
{
    const int b = blockIdx.x;
    const int t = threadIdx.x;

    __shared__ __align__(16) float lds[2560];
    float* bufL = lds;                         // stride STP
    float* bufR = lds + N*STP;                 // stride STP
    float* xB   = lds + 2*N*STP;               // stride HID (broadcast-read only)
    float* pool = lds + 2*N*STP + N*HID;       // batch(60)->lat(36)->e(144)
    unsigned char* pairs8 = (unsigned char*)&lds[2544];  // 64 B compacted pair list

    const v2f z2 = {0.f, 0.f};
    const v4f z4 = {0.f, 0.f, 0.f, 0.f};
    const v4f s4 = {SLOPE, SLOPE, SLOPE, SLOPE};

    // score-pair decomposition (144 pairs, 3 slots of 64/64/16)
    const int p0 = t,        i0 = p0 / N, j0 = p0 - i0*N;
    const int p1 = t + 64,   i1 = p1 / N, j1 = p1 - i1*N;
    const int p2 = (t < 16) ? (t + 128) : 143;
    const int i2 = p2 / N,   j2 = p2 - i2*N;

    // ---- stage batch into pool, emit passthrough outputs 0/1 ----
    if (t < N*5) {
        float v = batch[b*(N*5) + t];
        pool[t] = v;
        int i = t / 5, f = t - i*5;
        if (f < 4) out[OUT0 + (size_t)b*(N*4) + i*4 + f] = v;
        else       out[OUT1 + (size_t)b*N + i] = v;
    }
    __syncthreads();

    // ---- encoder layer 1 ----
    {
        float acc[N];
        float bias = enc_b1[t];
        #pragma unroll
        for (int i=0;i<N;i++) acc[i] = bias;
        #pragma unroll
        for (int f=0; f<5; f++) {
            float w = enc_w1[f*HID + t];
            #pragma unroll
            for (int i=0;i<N;i++) acc[i] = fmaf(pool[i*5+f], w, acc[i]);
        }
        #pragma unroll
        for (int i=0;i<N;i++) bufL[i*STP + t] = fmaxf(acc[i], 0.f);
    }
    __syncthreads();

    // ---- encoder layer 2 (fp32 weights; K-loop ROLLED) ----
    {
        v2f acc[N];
        #pragma unroll
        for (int i=0;i<N;i++) acc[i] = z2;
        const float* w2p = TW ? (wsT + t*HID) : nullptr;
        for (int c=0;c<HID;c+=4) {
            v2f w01, w23;
            if (TW) {
                v4f w4 = *reinterpret_cast<const v4f*>(&w2p[c]);
                w01 = w4.xy; w23 = w4.zw;
            } else {
                w01 = (v2f){enc_w2[(c+0)*HID+t], enc_w2[(c+1)*HID+t]};
                w23 = (v2f){enc_w2[(c+2)*HID+t], enc_w2[(c+3)*HID+t]};
            }
            #pragma unroll
            for (int i=0;i<N;i++) {
                v4f xv = *reinterpret_cast<const v4f*>(&bufL[i*STP + c]);
                acc[i] = __builtin_elementwise_fma(xv.xy, w01, acc[i]);
                acc[i] = __builtin_elementwise_fma(xv.zw, w23, acc[i]);
            }
        }
        float bias = enc_b2[t];
        #pragma unroll
        for (int i=0;i<N;i++) bufR[i*STP + t] = fmaxf(bias + acc[i].x + acc[i].y, 0.f);
    }
    __syncthreads();

    // ---- latent = h2 @ W3 + b3 (lanes 0..35) -> pool[0..35] ----
    if (t < N*3) {
        int i = t / 3, c = t - i*3;
        float acc = enc_b3[c];
        for (int k=0;k<HID;k+=4) {
            v4f xv = *reinterpret_cast<const v4f*>(&bufR[i*STP + k]);
            acc = fmaf(xv.x, enc_w3[(k+0)*3+c], acc);
            acc = fmaf(xv.y, enc_w3[(k+1)*3+c], acc);
            acc = fmaf(xv.z, enc_w3[(k+2)*3+c], acc);
            acc = fmaf(xv.w, enc_w3[(k+3)*3+c], acc);
        }
        pool[t] = acc;
        out[OUT4 + (size_t)b*(N*3) + t] = acc;
    }
    __syncthreads();

    // ---- skip connection -> registers ----
    float skipv[N];
    {
        float w0 = skip_w[t], w1 = skip_w[HID+t], w2 = skip_w[2*HID+t];
        float bias = skip_b[t];
        #pragma unroll
        for (int i=0;i<N;i++) {
            float v = bias;
            v = fmaf(pool[i*3+0], w0, v);
            v = fmaf(pool[i*3+1], w1, v);
            v = fmaf(pool[i*3+2], w2, v);
            skipv[i] = v;
        }
    }

    // ---- Gabriel adjacency via ballots ----
    auto gab = [&](int i, int j)->bool {
        if (i == j) return false;
        float pix = pool[i*3], piy = pool[i*3+1];
        float pjx = pool[j*3], pjy = pool[j*3+1];
        float mx = (pix + pjx) * 0.5f, my = (piy + pjy) * 0.5f;
        float dx = pix - pjx, dy = piy - pjy;
        float r2 = (dx*dx + dy*dy) * 0.25f;
        bool g = true;
        #pragma unroll
        for (int k=0;k<N;k++) {
            float ex = pool[k*3] - mx, ey = pool[k*3+1] - my;
            bool ok = (k == i) || (k == j) || (ex*ex + ey*ey > r2);
            g = g && ok;
        }
        return g;
    };
    unsigned long long gb0 = __ballot(gab(i0, j0));
    unsigned long long gb1 = __ballot(gab(i1, j1));
    unsigned long long gb2 = __ballot((t < 16) && gab(i2, j2));
    auto gbit = [&](int p)->int {
        unsigned long long m = (p < 64) ? gb0 : ((p < 128) ? gb1 : gb2);
        return (int)((m >> (p & 63)) & 1ull);
    };
    const int adjA = gbit(p0) | gbit(j0*N+i0) | (i0 == j0);
    const int adjB = gbit(p1) | gbit(j1*N+i1) | (i1 == j1);
    const int adjC = (t < 16) ? (gbit(p2) | gbit(j2*N+i2) | (i2 == j2)) : 0;

    // ---- compact valid pairs (Gabriel: nv <= 68, typically ~50) ----
    auto mbcnt64 = [&](unsigned long long m)->int {
        return __builtin_amdgcn_mbcnt_hi((unsigned)(m >> 32),
               __builtin_amdgcn_mbcnt_lo((unsigned)m, 0));
    };
    const unsigned long long am0 = __ballot(adjA != 0);
    const unsigned long long am1 = __ballot(adjB != 0);
    const unsigned long long am2 = __ballot(adjC != 0);
    const int c0  = __popcll(am0);
    const int c01 = c0 + __popcll(am1);
    const int nv  = c01 + __popcll(am2);
    const int idx0 = mbcnt64(am0);            // always < 64
    const int idx1 = c0  + mbcnt64(am1);
    const int idx2 = c01 + mbcnt64(am2);
    if (adjA)               pairs8[idx0] = (unsigned char)p0;
    if (adjB && idx1 < 64)  pairs8[idx1] = (unsigned char)p1;
    if (adjC && idx2 < 64)  pairs8[idx2] = (unsigned char)p2;
    const bool ovB = adjB && (idx1 >= 64);    // overflow pairs (<=4), owner-processed
    const bool ovC = adjC && (idx2 >= 64);
    const int nvc = nv < 64 ? nv : 64;

    // ---- score for one adjacent pair (h-loop ROLLED) ----
    auto scoreAt = [&](int i, int j, const float* __restrict__ att)->float {
        const float* Lj = &bufL[j*STP];
        const float* Ri = &bufR[i*STP];
        v4f a = z4;
        for (int h=0; h<HID; h+=4) {
            v4f a4 = *reinterpret_cast<const v4f*>(&att[h]);   // uniform -> scalar load
            v4f xl = *reinterpret_cast<const v4f*>(Lj + h);
            v4f xr = *reinterpret_cast<const v4f*>(Ri + h);
            v4f s = xl + xr;
            v4f l = __builtin_elementwise_fma(s4, __builtin_elementwise_min(s, z4),
                                              __builtin_elementwise_max(s, z4));
            a = __builtin_elementwise_fma(a4, l, a);
        }
        return (a.x + a.y) + (a.z + a.w);
    };

    // ---- GATv2 core: sparse score -> softmax -> aggregate ----
    auto gat_core = [&](const float* __restrict__ att, const float* __restrict__ gb,
                        float* __restrict__ xout, int strideOut, int useSkip) {
        __syncthreads();   // staged xl/xr visible
        // init e to -1e9 (matches reference mask), then scatter real scores
        pool[t] = -1e9f; pool[t+64] = -1e9f;
        if (t < 16) pool[t+128] = -1e9f;
        if (t < nvc) {
            int p = pairs8[t];
            int i = (p * 171) >> 11;           // p/12 for p<144
            int j = p - i*N;
            pool[p] = scoreAt(i, j, att);
        }
        if (nv > 64) {                          // rare (<=4 pairs)
            if (ovB) pool[p1] = scoreAt(i1, j1, att);
            if (ovC) pool[p2] = scoreAt(i2, j2, att);
        }
        __syncthreads();
        if (t < N) {   // row softmax
            float m = -2e9f;
            #pragma unroll
            for (int j=0;j<N;j++) m = fmaxf(m, pool[t*N+j]);
            float tmp[N]; float sum = 0.f;
            #pragma unroll
            for (int j=0;j<N;j++) { float v = __expf(pool[t*N+j] - m); tmp[j] = v; sum += v; }
            float inv = 1.0f / sum;
            #pragma unroll
            for (int j=0;j<N;j++) pool[t*N+j] = tmp[j] * inv;
        }
        __syncthreads();
        {
            float xj[N];
            #pragma unroll
            for (int j=0;j<N;j++) xj[j] = bufL[j*STP + t];
            v4f X0 = {xj[0], xj[1], xj[2],  xj[3]};
            v4f X1 = {xj[4], xj[5], xj[6],  xj[7]};
            v4f X2 = {xj[8], xj[9], xj[10], xj[11]};
            float bias = gb[t];
            #pragma unroll
            for (int i=0;i<N;i++) {
                const v4f* ep = reinterpret_cast<const v4f*>(&pool[i*N]);
                v4f acc = __builtin_elementwise_fma(ep[0], X0,
                          __builtin_elementwise_fma(ep[1], X1, ep[2]*X2));
                float r = bias + ((acc.x + acc.y) + (acc.z + acc.w));
                if (useSkip) r = fmaf(ALPHA, skipv[i], r);
                xout[i*strideOut + t] = fmaxf(r, 0.f);
            }
        }
        __syncthreads();
    };

    // ---- stage xl/xr (bf16 weights when TW; K-loop ROLLED) ----
    auto stage = [&](const float* __restrict__ xin, int strideIn,
                     const unsigned* __restrict__ wlB, const unsigned* __restrict__ wrB,
                     const float* __restrict__ wl, const float* __restrict__ wr) {
        v2f al[N], ar[N];
        #pragma unroll
        for (int i=0;i<N;i++) { al[i] = z2; ar[i] = z2; }
        for (int c=0;c<HID;c+=4) {
            v2f wl01, wl23, wr01, wr23;
            if (TW) {
                uint2 qa = *reinterpret_cast<const uint2*>(wlB + (c>>1));
                uint2 qb = *reinterpret_cast<const uint2*>(wrB + (c>>1));
                wl01 = (v2f){ __uint_as_float(qa.x << 16), __uint_as_float(qa.x & 0xffff0000u) };
                wl23 = (v2f){ __uint_as_float(qa.y << 16), __uint_as_float(qa.y & 0xffff0000u) };
                wr01 = (v2f){ __uint_as_float(qb.x << 16), __uint_as_float(qb.x & 0xffff0000u) };
                wr23 = (v2f){ __uint_as_float(qb.y << 16), __uint_as_float(qb.y & 0xffff0000u) };
            } else {
                wl01 = (v2f){wl[(c+0)*HID+t], wl[(c+1)*HID+t]};
                wl23 = (v2f){wl[(c+2)*HID+t], wl[(c+3)*HID+t]};
                wr01 = (v2f){wr[(c+0)*HID+t], wr[(c+1)*HID+t]};
                wr23 = (v2f){wr[(c+2)*HID+t], wr[(c+3)*HID+t]};
            }
            #pragma unroll
            for (int i=0;i<N;i++) {
                v4f xv = *reinterpret_cast<const v4f*>(&xin[i*strideIn + c]);
                al[i] = __builtin_elementwise_fma(xv.xy, wl01, al[i]);
                al[i] = __builtin_elementwise_fma(xv.zw, wl23, al[i]);
                ar[i] = __builtin_elementwise_fma(xv.xy, wr01, ar[i]);
                ar[i] = __builtin_elementwise_fma(xv.zw, wr23, ar[i]);
            }
        }
        #pragma unroll
        for (int i=0;i<N;i++) {
            bufL[i*STP + t] = al[i].x + al[i].y;
            bufR[i*STP + t] = ar[i].x + ar[i].y;
        }
    };

    // per-lane bf16 weight rows (32 dwords each)
    const unsigned* wb = TW ? (const unsigned*)(wsT + 4096) : nullptr;
    const unsigned* w_g2l = TW ? wb + 0*2048 + t*32 : nullptr;
    const unsigned* w_g2r = TW ? wb + 1*2048 + t*32 : nullptr;
    const unsigned* w_g3l = TW ? wb + 2*2048 + t*32 : nullptr;
    const unsigned* w_g3r = TW ? wb + 3*2048 + t*32 : nullptr;
    const unsigned* w_g4l = TW ? wb + 4*2048 + t*32 : nullptr;
    const unsigned* w_g4r = TW ? wb + 5*2048 + t*32 : nullptr;

    // ---- GAT layer 1 (cin = 1; x0 = lat[:,2] from pool) ----
    {
        float wlv = g1_wl[t], wrv = g1_wr[t];
        #pragma unroll
        for (int i=0;i<N;i++) {
            float v = pool[i*3+2];
            bufL[i*STP + t] = v * wlv;
            bufR[i*STP + t] = v * wrv;
        }
    }
    gat_core(g1_att, g1_b, bufR, STP, 0);   // x1 -> bufR

    // ---- GAT layer 2 ----
    stage(bufR, STP, w_g2l, w_g2r, g2_wl, g2_wr);
    gat_core(g2_att, g2_b, xB, HID, 0);     // x2 -> xB (persists)

    // ---- GAT layer 3 ----
    stage(xB, HID, w_g3l, w_g3r, g3_wl, g3_wr);
    gat_core(g3_att, g3_b, bufR, STP, 1);   // x3 -> bufR

    // ---- logits head: x3 @ lab_w + lab_b ----
    if (t < N*4) {
        int i = t >> 2, c = t & 3;
        float acc = lab_b[c];
        if (TW) {
            const float* lwT = wsT + 10240 + c*HID;
            for (int h=0;h<HID;h+=4) {
                v4f xv = *reinterpret_cast<const v4f*>(&bufR[i*STP + h]);
                v4f w4 = *reinterpret_cast<const v4f*>(&lwT[h]);
                acc = fmaf(xv.x, w4.x, acc);
                acc = fmaf(xv.y, w4.y, acc);
                acc = fmaf(xv.z, w4.z, acc);
                acc = fmaf(xv.w, w4.w, acc);
            }
        } else {
            for (int h=0;h<HID;h+=4) {
                v4f xv = *reinterpret_cast<const v4f*>(&bufR[i*STP + h]);
                acc = fmaf(xv.x, lab_w[(h+0)*4+c], acc);
                acc = fmaf(xv.y, lab_w[(h+1)*4+c], acc);
                acc = fmaf(xv.z, lab_w[(h+2)*4+c], acc);
                acc = fmaf(xv.w, lab_w[(h+3)*4+c], acc);
            }
        }
        out[OUT2 + (size_t)b*(N*4) + t] = acc;
    }

    // ---- GAT layer 4 ----
    stage(xB, HID, w_g4l, w_g4r, g4_wl, g4_wr);
    gat_core(g4_att, g4_b, bufR, STP, 1);   // x4 -> bufR

    // ---- values head ----
    if (t < N) {
        float acc = val_b[0];
        for (int h=0;h<HID;h+=4) {
            v4f xv = *reinterpret_cast<const v4f*>(&bufR[t*STP + h]);
            v4f w4 = *reinterpret_cast<const v4f*>(&val_w[h]);
            acc = fmaf(xv.x, w4.x, acc);
            acc = fmaf(xv.y, w4.y, acc);
            acc = fmaf(xv.z, w4.z, acc);
            acc = fmaf(xv.w, w4.w, acc);
        }
        out[OUT3 + (size_t)b*N + t] = acc;
    }
}

extern "C" void kernel_launch(void* const* d_in, const int* in_sizes, int n_in,
                              void* d_out, int out_size, void* d_ws, size_t ws_size,
                              hipStream_t stream) {
    (void)in_sizes; (void)n_in; (void)out_size;
    const bool useT = (ws_size >= (7*4096 + 256)*sizeof(float));
    if (useT) {
        prep_kernel<<<dim3(449), dim3(64), 0, stream>>>(
            (const float*)d_in[3],
            (const float*)d_in[11], (const float*)d_in[12],
            (const float*)d_in[15], (const float*)d_in[16],
            (const float*)d_in[19], (const float*)d_in[20],
            (const float*)d_in[23],
            (float*)d_ws);
        gae_kernel<true><<<dim3(4096), dim3(64), 0, stream>>>(
            (const float*)d_in[0],
            (const float*)d_in[1],  (const float*)d_in[2],
            (const float*)d_in[3],  (const float*)d_in[4],
            (const float*)d_in[5],  (const float*)d_in[6],
            (const float*)d_in[7],  (const float*)d_in[8],  (const float*)d_in[9],  (const float*)d_in[10],
            (const float*)d_in[11], (const float*)d_in[12], (const float*)d_in[13], (const float*)d_in[14],
            (const float*)d_in[15], (const float*)d_in[16], (const float*)d_in[17], (const float*)d_in[18],
            (const float*)d_in[19], (const float*)d_in[20], (const float*)d_in[21], (const float*)d_in[22],
            (const float*)d_in[23], (const float*)d_in[24],
            (const float*)d_in[25], (const float*)d_in[26],
            (const float*)d_in[27], (const float*)d_in[28],
            (const float*)d_ws,
            (float*)d_out);
    } else {
        gae_kernel<false><<<dim3(4096), dim3(64), 0, stream>>>(
            (const float*)d_in[0],
            (const float*)d_in[1],  (const float*)d_in[2],
            (const float*)d_in[3],  (const float*)d_in[4],
            (const float*)d_in[5],  (const float*)d_in[6],
            (const float*)d_in[7],  (const float*)d_in[8],  (const float*)d_in[9],  (const float*)d_in[10],
            (const float*)d_in[11], (const float*)d_in[12], (const float*)d_in[13], (const float*)d_in[14],
            (const float*)d_in[15], (const float*)d_in[16], (const float*)d_in[17], (const float*)d_in[18],
            (const float*)d_in[19], (const float*)d_in[20], (const float*)d_in[21], (const float*)d_in[22],
            (const float*)d_in[23], (const float*)d_in[24],
            (const float*)d_in[25], (const float*)d_in[26],
            (const float*)d_in[27], (const float*)d_in[28],
            nullptr,
            (float*)d_out);
    }
}

// Round 9
// 150.940 us; speedup vs baseline: 2.2111x; 1.2108x over previous
//
#include <hip/hip_runtime.h>
#include <hip/hip_bf16.h>
#include <math.h>

#define N     12
#define HID   64
#define STP   68     // padded row stride for bufL/bufR (272 B rows, 16B-aligned)
#define SLOPE 0.2f
#define ALPHA 0.1f

typedef float v2f __attribute__((ext_vector_type(2)));
typedef float v4f __attribute__((ext_vector_type(4)));
typedef int   i4  __attribute__((ext_vector_type(4)));
typedef short v8s __attribute__((ext_vector_type(8)));

static __device__ __forceinline__ v8s as_v8s(i4 v) {
    union { i4 a; v8s b; } u; u.a = v; return u.b;
}

// flat output offsets (float32 elements)
#define OUT0 0          // batch[:,:,:4]
#define OUT1 196608     // batch[:,:,4:5]
#define OUT2 245760     // logits
#define OUT3 442368     // values
#define OUT4 491520     // latent

// ws layout (float offsets):
//   [0,4096)         enc_w2 transposed fp32 (enc path stays fp32: latent feeds the
//                    Gabriel d2>r2 comparisons -> adjacency must be bit-exact)
//   [4096,16384)     6 GAT matrices (g2wl,g2wr,g3wl,g3wr,g4wl,g4wr) pre-packed in
//                    MFMA B-fragment layout, bf16. Per matrix 2048 dwords laid out
//                    [kt][nt][lane][4 dwords]; element j of lane's frag =
//                    bf16( W[(kt*32 + (lane>>4)*8 + j)*64 + nt*16 + (lane&15)] )
//   [16384,16640)    labT fp32: labT[c*64+h] = lab_w[h*4+c]
__global__ void prep_kernel(const float* __restrict__ enc_w2,
                            const float* __restrict__ g2_wl, const float* __restrict__ g2_wr,
                            const float* __restrict__ g3_wl, const float* __restrict__ g3_wr,
                            const float* __restrict__ g4_wl, const float* __restrict__ g4_wr,
                            const float* __restrict__ lab_w,
                            float* __restrict__ ws) {
    int t = threadIdx.x;
    int bx = blockIdx.x;
    if (bx < 64) {                       // enc_w2 fp32 transpose
        int c = bx;
        ws[t*64 + c] = enc_w2[c*64 + t];
        return;
    }
    if (bx == 112) {                     // labT
        #pragma unroll
        for (int c = 0; c < 4; c++) ws[16384 + c*64 + t] = lab_w[t*4 + c];
        return;
    }
    // B-fragment pack: 48 blocks = 6 matrices x 2 kt x 4 nt
    int idx = bx - 64;
    int mat = idx >> 3, rem = idx & 7;
    int kt = rem >> 2, nt = rem & 3;
    const float* src;
    switch (mat) {
        case 0: src = g2_wl; break;
        case 1: src = g2_wr; break;
        case 2: src = g3_wl; break;
        case 3: src = g3_wr; break;
        case 4: src = g4_wl; break;
        default: src = g4_wr; break;
    }
    int quad = t >> 4, col = t & 15;
    int n = nt*16 + col;
    unsigned* dst = (unsigned*)(ws + 4096) + mat*2048 + (kt*4+nt)*256 + t*4;
    #pragma unroll
    for (int jp = 0; jp < 4; jp++) {
        int k0 = kt*32 + quad*8 + 2*jp;
        __hip_bfloat16 h0 = __float2bfloat16(src[(k0+0)*64 + n]);
        __hip_bfloat16 h1 = __float2bfloat16(src[(k0+1)*64 + n]);
        unsigned u0 = *(unsigned short*)&h0, u1 = *(unsigned short*)&h1;
        dst[jp] = u0 | (u1 << 16);
    }
}

// One graph per 64-lane wave (R7: multi-wave blocks convoy on barriers).
// LDS: bufL(816)+bufR(816)+xB(768)+pool(144)+pairs(16) = 2560 floats = 10240 B
//   -> 16 blocks/CU.
// R3/R4: keep 16-iter fp32 K-loops ROLLED (full unroll spills to scratch).
// R5:    padded stride, not rotate swizzle.
// R8:    sparse score (Gabriel <=68 valid of 144 pairs); bf16 GAT weights.
// R9:    stage matmuls via mfma_f32_16x16x32_bf16 (12x64 @ 64x64 x2): 16 MFMA +
//        16 coalesced B loads replace ~1000 VALU/LDS ops per stage.
template<bool TW>
__global__ __launch_bounds__(64, 3) void gae_kernel(
    const float* __restrict__ batch,
    const float* __restrict__ enc_w1, const float* __restrict__ enc_b1,
    const float* __restrict__ enc_w2, const float* __restrict__ enc_b2,
    const float* __restrict__ enc_w3, const float* __restrict__ enc_b3,
    const float* __restrict__ g1_wl, const float* __restrict__ g1_wr,
    const float* __restrict__ g1_att, const float* __restrict__ g1_b,
    const float* __restrict__ g2_wl, const float* __restrict__ g2_wr,
    const float* __restrict__ g2_att, const float* __restrict__ g2_b,
    const float* __restrict__ g3_wl, const float* __restrict__ g3_wr,
    const float* __restrict__ g3_att, const float* __restrict__ g3_b,
    const float* __restrict__ g4_wl, const float* __restrict__ g4_wr,
    const float* __restrict__ g4_att, const float* __restrict__ g4_b,
    const float* __restrict__ lab_w, const float* __restrict__ lab_b,
    const float* __restrict__ val_w, const float* __restrict__ val_b,
    const float* __restrict__ skip_w, const float* __restrict__ skip_b,
    const float* __restrict__ wsT,
    float* __restrict__ out)
{
    const int b = blockIdx.x;
    const int t = threadIdx.x;

    __shared__ __align__(16) float lds[2560];
    float* bufL = lds;                         // stride STP
    float* bufR = lds + N*STP;                 // stride STP
    float* xB   = lds + 2*N*STP;               // stride HID (broadcast-read only)
    float* pool = lds + 2*N*STP + N*HID;       // batch(60)->lat(36)->e(144)
    unsigned char* pairs8 = (unsigned char*)&lds[2544];  // 64 B compacted pair list

    const v2f z2 = {0.f, 0.f};
    const v4f z4 = {0.f, 0.f, 0.f, 0.f};
    const v4f s4 = {SLOPE, SLOPE, SLOPE, SLOPE};

    // score-pair decomposition (144 pairs, 3 slots of 64/64/16)
    const int p0 = t,        i0 = p0 / N, j0 = p0 - i0*N;
    const int p1 = t + 64,   i1 = p1 / N, j1 = p1 - i1*N;
    const int p2 = (t < 16) ? (t + 128) : 143;
    const int i2 = p2 / N,   j2 = p2 - i2*N;

    // ---- stage batch into pool, emit passthrough outputs 0/1 ----
    if (t < N*5) {
        float v = batch[b*(N*5) + t];
        pool[t] = v;
        int i = t / 5, f = t - i*5;
        if (f < 4) out[OUT0 + (size_t)b*(N*4) + i*4 + f] = v;
        else       out[OUT1 + (size_t)b*N + i] = v;
    }
    __syncthreads();

    // ---- encoder layer 1 ----
    {
        float acc[N];
        float bias = enc_b1[t];
        #pragma unroll
        for (int i=0;i<N;i++) acc[i] = bias;
        #pragma unroll
        for (int f=0; f<5; f++) {
            float w = enc_w1[f*HID + t];
            #pragma unroll
            for (int i=0;i<N;i++) acc[i] = fmaf(pool[i*5+f], w, acc[i]);
        }
        #pragma unroll
        for (int i=0;i<N;i++) bufL[i*STP + t] = fmaxf(acc[i], 0.f);
    }
    __syncthreads();

    // ---- encoder layer 2 (fp32; K-loop ROLLED) ----
    {
        v2f acc[N];
        #pragma unroll
        for (int i=0;i<N;i++) acc[i] = z2;
        const float* w2p = TW ? (wsT + t*HID) : nullptr;
        for (int c=0;c<HID;c+=4) {
            v2f w01, w23;
            if (TW) {
                v4f w4 = *reinterpret_cast<const v4f*>(&w2p[c]);
                w01 = w4.xy; w23 = w4.zw;
            } else {
                w01 = (v2f){enc_w2[(c+0)*HID+t], enc_w2[(c+1)*HID+t]};
                w23 = (v2f){enc_w2[(c+2)*HID+t], enc_w2[(c+3)*HID+t]};
            }
            #pragma unroll
            for (int i=0;i<N;i++) {
                v4f xv = *reinterpret_cast<const v4f*>(&bufL[i*STP + c]);
                acc[i] = __builtin_elementwise_fma(xv.xy, w01, acc[i]);
                acc[i] = __builtin_elementwise_fma(xv.zw, w23, acc[i]);
            }
        }
        float bias = enc_b2[t];
        #pragma unroll
        for (int i=0;i<N;i++) bufR[i*STP + t] = fmaxf(bias + acc[i].x + acc[i].y, 0.f);
    }
    __syncthreads();

    // ---- latent = h2 @ W3 + b3 (lanes 0..35) -> pool[0..35] ----
    if (t < N*3) {
        int i = t / 3, c = t - i*3;
        float acc = enc_b3[c];
        for (int k=0;k<HID;k+=4) {
            v4f xv = *reinterpret_cast<const v4f*>(&bufR[i*STP + k]);
            acc = fmaf(xv.x, enc_w3[(k+0)*3+c], acc);
            acc = fmaf(xv.y, enc_w3[(k+1)*3+c], acc);
            acc = fmaf(xv.z, enc_w3[(k+2)*3+c], acc);
            acc = fmaf(xv.w, enc_w3[(k+3)*3+c], acc);
        }
        pool[t] = acc;
        out[OUT4 + (size_t)b*(N*3) + t] = acc;
    }
    __syncthreads();

    // ---- skip connection -> registers ----
    float skipv[N];
    {
        float w0 = skip_w[t], w1 = skip_w[HID+t], w2 = skip_w[2*HID+t];
        float bias = skip_b[t];
        #pragma unroll
        for (int i=0;i<N;i++) {
            float v = bias;
            v = fmaf(pool[i*3+0], w0, v);
            v = fmaf(pool[i*3+1], w1, v);
            v = fmaf(pool[i*3+2], w2, v);
            skipv[i] = v;
        }
    }

    // ---- Gabriel adjacency via ballots ----
    auto gab = [&](int i, int j)->bool {
        if (i == j) return false;
        float pix = pool[i*3], piy = pool[i*3+1];
        float pjx = pool[j*3], pjy = pool[j*3+1];
        float mx = (pix + pjx) * 0.5f, my = (piy + pjy) * 0.5f;
        float dx = pix - pjx, dy = piy - pjy;
        float r2 = (dx*dx + dy*dy) * 0.25f;
        bool g = true;
        #pragma unroll
        for (int k=0;k<N;k++) {
            float ex = pool[k*3] - mx, ey = pool[k*3+1] - my;
            bool ok = (k == i) || (k == j) || (ex*ex + ey*ey > r2);
            g = g && ok;
        }
        return g;
    };
    unsigned long long gb0 = __ballot(gab(i0, j0));
    unsigned long long gb1 = __ballot(gab(i1, j1));
    unsigned long long gb2 = __ballot((t < 16) && gab(i2, j2));
    auto gbit = [&](int p)->int {
        unsigned long long m = (p < 64) ? gb0 : ((p < 128) ? gb1 : gb2);
        return (int)((m >> (p & 63)) & 1ull);
    };
    const int adjA = gbit(p0) | gbit(j0*N+i0) | (i0 == j0);
    const int adjB = gbit(p1) | gbit(j1*N+i1) | (i1 == j1);
    const int adjC = (t < 16) ? (gbit(p2) | gbit(j2*N+i2) | (i2 == j2)) : 0;

    // ---- compact valid pairs ----
    auto mbcnt64 = [&](unsigned long long m)->int {
        return __builtin_amdgcn_mbcnt_hi((unsigned)(m >> 32),
               __builtin_amdgcn_mbcnt_lo((unsigned)m, 0));
    };
    const unsigned long long am0 = __ballot(adjA != 0);
    const unsigned long long am1 = __ballot(adjB != 0);
    const unsigned long long am2 = __ballot(adjC != 0);
    const int c0  = __popcll(am0);
    const int c01 = c0 + __popcll(am1);
    const int nv  = c01 + __popcll(am2);
    const int idx0 = mbcnt64(am0);
    const int idx1 = c0  + mbcnt64(am1);
    const int idx2 = c01 + mbcnt64(am2);
    if (adjA)               pairs8[idx0] = (unsigned char)p0;
    if (adjB && idx1 < 64)  pairs8[idx1] = (unsigned char)p1;
    if (adjC && idx2 < 64)  pairs8[idx2] = (unsigned char)p2;
    const bool ovB = adjB && (idx1 >= 64);
    const bool ovC = adjC && (idx2 >= 64);
    const int nvc = nv < 64 ? nv : 64;

    // ---- score for one adjacent pair (h-loop ROLLED) ----
    auto scoreAt = [&](int i, int j, const float* __restrict__ att)->float {
        const float* Lj = &bufL[j*STP];
        const float* Ri = &bufR[i*STP];
        v4f a = z4;
        for (int h=0; h<HID; h+=4) {
            v4f a4 = *reinterpret_cast<const v4f*>(&att[h]);
            v4f xl = *reinterpret_cast<const v4f*>(Lj + h);
            v4f xr = *reinterpret_cast<const v4f*>(Ri + h);
            v4f s = xl + xr;
            v4f l = __builtin_elementwise_fma(s4, __builtin_elementwise_min(s, z4),
                                              __builtin_elementwise_max(s, z4));
            a = __builtin_elementwise_fma(a4, l, a);
        }
        return (a.x + a.y) + (a.z + a.w);
    };

    // ---- GATv2 core: sparse score -> softmax -> aggregate ----
    auto gat_core = [&](const float* __restrict__ att, const float* __restrict__ gb,
                        float* __restrict__ xout, int strideOut, int useSkip) {
        __syncthreads();
        pool[t] = -1e9f; pool[t+64] = -1e9f;
        if (t < 16) pool[t+128] = -1e9f;
        if (t < nvc) {
            int p = pairs8[t];
            int i = (p * 171) >> 11;           // p/12 for p<144
            int j = p - i*N;
            pool[p] = scoreAt(i, j, att);
        }
        if (nv > 64) {
            if (ovB) pool[p1] = scoreAt(i1, j1, att);
            if (ovC) pool[p2] = scoreAt(i2, j2, att);
        }
        __syncthreads();
        if (t < N) {   // row softmax
            float m = -2e9f;
            #pragma unroll
            for (int j=0;j<N;j++) m = fmaxf(m, pool[t*N+j]);
            float tmp[N]; float sum = 0.f;
            #pragma unroll
            for (int j=0;j<N;j++) { float v = __expf(pool[t*N+j] - m); tmp[j] = v; sum += v; }
            float inv = 1.0f / sum;
            #pragma unroll
            for (int j=0;j<N;j++) pool[t*N+j] = tmp[j] * inv;
        }
        __syncthreads();
        {
            float xj[N];
            #pragma unroll
            for (int j=0;j<N;j++) xj[j] = bufL[j*STP + t];
            v4f X0 = {xj[0], xj[1], xj[2],  xj[3]};
            v4f X1 = {xj[4], xj[5], xj[6],  xj[7]};
            v4f X2 = {xj[8], xj[9], xj[10], xj[11]};
            float bias = gb[t];
            #pragma unroll
            for (int i=0;i<N;i++) {
                const v4f* ep = reinterpret_cast<const v4f*>(&pool[i*N]);
                v4f acc = __builtin_elementwise_fma(ep[0], X0,
                          __builtin_elementwise_fma(ep[1], X1, ep[2]*X2));
                float r = bias + ((acc.x + acc.y) + (acc.z + acc.w));
                if (useSkip) r = fmaf(ALPHA, skipv[i], r);
                xout[i*strideOut + t] = fmaxf(r, 0.f);
            }
        }
        __syncthreads();
    };

    // ---- MFMA stage (TW only): bufL/bufR <- xin @ {wl, wr} (bf16) ----
    // A[m=lane&15][k=quad*8+j]; B pre-packed (prep); C/D: col=lane&15, row=quad*4+reg.
    auto stage_mfma = [&](const float* __restrict__ xin, int strideIn, int matL) {
        const int m = t & 15, quad = t >> 4;
        const int mc = (m < N) ? m : 0;        // clamp: rows 12..15 discarded anyway
        i4 aF[2];
        #pragma unroll
        for (int kt=0; kt<2; kt++) {
            const float* xp = &xin[mc*strideIn + kt*32 + quad*8];
            v4f lo = *reinterpret_cast<const v4f*>(xp);
            v4f hi = *reinterpret_cast<const v4f*>(xp + 4);
            unsigned u0 = __float_as_uint(lo.x) + 0x8000u, u1 = __float_as_uint(lo.y) + 0x8000u;
            unsigned u2 = __float_as_uint(lo.z) + 0x8000u, u3 = __float_as_uint(lo.w) + 0x8000u;
            unsigned u4 = __float_as_uint(hi.x) + 0x8000u, u5 = __float_as_uint(hi.y) + 0x8000u;
            unsigned u6 = __float_as_uint(hi.z) + 0x8000u, u7 = __float_as_uint(hi.w) + 0x8000u;
            i4 a;
            a.x = (int)__builtin_amdgcn_perm(u1, u0, 0x07060302u);
            a.y = (int)__builtin_amdgcn_perm(u3, u2, 0x07060302u);
            a.z = (int)__builtin_amdgcn_perm(u5, u4, 0x07060302u);
            a.w = (int)__builtin_amdgcn_perm(u7, u6, 0x07060302u);
            aF[kt] = a;
        }
        const i4* bbase = reinterpret_cast<const i4*>(wsT + 4096);
        #pragma unroll
        for (int mm=0; mm<2; mm++) {
            const i4* bp = bbase + (matL + mm)*512;
            v4f acc[4] = {z4, z4, z4, z4};
            #pragma unroll
            for (int nt=0; nt<4; nt++) {
                i4 b0 = bp[(0*4+nt)*64 + t];
                i4 b1 = bp[(1*4+nt)*64 + t];
                acc[nt] = __builtin_amdgcn_mfma_f32_16x16x32_bf16(as_v8s(aF[0]), as_v8s(b0), acc[nt], 0, 0, 0);
                acc[nt] = __builtin_amdgcn_mfma_f32_16x16x32_bf16(as_v8s(aF[1]), as_v8s(b1), acc[nt], 0, 0, 0);
            }
            float* dst = (mm == 0) ? bufL : bufR;
            if (quad < 3) {
                #pragma unroll
                for (int nt=0; nt<4; nt++) {
                    #pragma unroll
                    for (int r=0; r<4; r++)
                        dst[(quad*4+r)*STP + nt*16 + m] = acc[nt][r];
                }
            }
        }
    };

    // ---- fp32 VALU stage (fallback when TW=false) ----
    auto stage = [&](const float* __restrict__ xin, int strideIn,
                     const float* __restrict__ wl, const float* __restrict__ wr) {
        v2f al[N], ar[N];
        #pragma unroll
        for (int i=0;i<N;i++) { al[i] = z2; ar[i] = z2; }
        for (int c=0;c<HID;c+=4) {
            v2f wl01 = (v2f){wl[(c+0)*HID+t], wl[(c+1)*HID+t]};
            v2f wl23 = (v2f){wl[(c+2)*HID+t], wl[(c+3)*HID+t]};
            v2f wr01 = (v2f){wr[(c+0)*HID+t], wr[(c+1)*HID+t]};
            v2f wr23 = (v2f){wr[(c+2)*HID+t], wr[(c+3)*HID+t]};
            #pragma unroll
            for (int i=0;i<N;i++) {
                v4f xv = *reinterpret_cast<const v4f*>(&xin[i*strideIn + c]);
                al[i] = __builtin_elementwise_fma(xv.xy, wl01, al[i]);
                al[i] = __builtin_elementwise_fma(xv.zw, wl23, al[i]);
                ar[i] = __builtin_elementwise_fma(xv.xy, wr01, ar[i]);
                ar[i] = __builtin_elementwise_fma(xv.zw, wr23, ar[i]);
            }
        }
        #pragma unroll
        for (int i=0;i<N;i++) {
            bufL[i*STP + t] = al[i].x + al[i].y;
            bufR[i*STP + t] = ar[i].x + ar[i].y;
        }
    };

    // ---- GAT layer 1 (cin = 1; x0 = lat[:,2] from pool) ----
    {
        float wlv = g1_wl[t], wrv = g1_wr[t];
        #pragma unroll
        for (int i=0;i<N;i++) {
            float v = pool[i*3+2];
            bufL[i*STP + t] = v * wlv;
            bufR[i*STP + t] = v * wrv;
        }
    }
    gat_core(g1_att, g1_b, bufR, STP, 0);   // x1 -> bufR

    // ---- GAT layer 2 ----
    if (TW) stage_mfma(bufR, STP, 0); else stage(bufR, STP, g2_wl, g2_wr);
    gat_core(g2_att, g2_b, xB, HID, 0);     // x2 -> xB (persists)

    // ---- GAT layer 3 ----
    if (TW) stage_mfma(xB, HID, 2); else stage(xB, HID, g3_wl, g3_wr);
    gat_core(g3_att, g3_b, bufR, STP, 1);   // x3 -> bufR

    // ---- logits head: x3 @ lab_w + lab_b ----
    if (t < N*4) {
        int i = t >> 2, c = t & 3;
        float acc = lab_b[c];
        if (TW) {
            const float* lwT = wsT + 16384 + c*HID;
            for (int h=0;h<HID;h+=4) {
                v4f xv = *reinterpret_cast<const v4f*>(&bufR[i*STP + h]);
                v4f w4 = *reinterpret_cast<const v4f*>(&lwT[h]);
                acc = fmaf(xv.x, w4.x, acc);
                acc = fmaf(xv.y, w4.y, acc);
                acc = fmaf(xv.z, w4.z, acc);
                acc = fmaf(xv.w, w4.w, acc);
            }
        } else {
            for (int h=0;h<HID;h+=4) {
                v4f xv = *reinterpret_cast<const v4f*>(&bufR[i*STP + h]);
                acc = fmaf(xv.x, lab_w[(h+0)*4+c], acc);
                acc = fmaf(xv.y, lab_w[(h+1)*4+c], acc);
                acc = fmaf(xv.z, lab_w[(h+2)*4+c], acc);
                acc = fmaf(xv.w, lab_w[(h+3)*4+c], acc);
            }
        }
        out[OUT2 + (size_t)b*(N*4) + t] = acc;
    }

    // ---- GAT layer 4 ----
    if (TW) stage_mfma(xB, HID, 4); else stage(xB, HID, g4_wl, g4_wr);
    gat_core(g4_att, g4_b, bufR, STP, 1);   // x4 -> bufR

    // ---- values head ----
    if (t < N) {
        float acc = val_b[0];
        for (int h=0;h<HID;h+=4) {
            v4f xv = *reinterpret_cast<const v4f*>(&bufR[t*STP + h]);
            v4f w4 = *reinterpret_cast<const v4f*>(&val_w[h]);
            acc = fmaf(xv.x, w4.x, acc);
            acc = fmaf(xv.y, w4.y, acc);
            acc = fmaf(xv.z, w4.z, acc);
            acc = fmaf(xv.w, w4.w, acc);
        }
        out[OUT3 + (size_t)b*N + t] = acc;
    }
}

extern "C" void kernel_launch(void* const* d_in, const int* in_sizes, int n_in,
                              void* d_out, int out_size, void* d_ws, size_t ws_size,
                              hipStream_t stream) {
    (void)in_sizes; (void)n_in; (void)out_size;
    const bool useT = (ws_size >= (16384 + 256)*sizeof(float));
    if (useT) {
        prep_kernel<<<dim3(113), dim3(64), 0, stream>>>(
            (const float*)d_in[3],
            (const float*)d_in[11], (const float*)d_in[12],
            (const float*)d_in[15], (const float*)d_in[16],
            (const float*)d_in[19], (const float*)d_in[20],
            (const float*)d_in[23],
            (float*)d_ws);
        gae_kernel<true><<<dim3(4096), dim3(64), 0, stream>>>(
            (const float*)d_in[0],
            (const float*)d_in[1],  (const float*)d_in[2],
            (const float*)d_in[3],  (const float*)d_in[4],
            (const float*)d_in[5],  (const float*)d_in[6],
            (const float*)d_in[7],  (const float*)d_in[8],  (const float*)d_in[9],  (const float*)d_in[10],
            (const float*)d_in[11], (const float*)d_in[12], (const float*)d_in[13], (const float*)d_in[14],
            (const float*)d_in[15], (const float*)d_in[16], (const float*)d_in[17], (const float*)d_in[18],
            (const float*)d_in[19], (const float*)d_in[20], (const float*)d_in[21], (const float*)d_in[22],
            (const float*)d_in[23], (const float*)d_in[24],
            (const float*)d_in[25], (const float*)d_in[26],
            (const float*)d_in[27], (const float*)d_in[28],
            (const float*)d_ws,
            (float*)d_out);
    } else {
        gae_kernel<false><<<dim3(4096), dim3(64), 0, stream>>>(
            (const float*)d_in[0],
            (const float*)d_in[1],  (const float*)d_in[2],
            (const float*)d_in[3],  (const float*)d_in[4],
            (const float*)d_in[5],  (const float*)d_in[6],
            (const float*)d_in[7],  (const float*)d_in[8],  (const float*)d_in[9],  (const float*)d_in[10],
            (const float*)d_in[11], (const float*)d_in[12], (const float*)d_in[13], (const float*)d_in[14],
            (const float*)d_in[15], (const float*)d_in[16], (const float*)d_in[17], (const float*)d_in[18],
            (const float*)d_in[19], (const float*)d_in[20], (const float*)d_in[21], (const float*)d_in[22],
            (const float*)d_in[23], (const float*)d_in[24],
            (const float*)d_in[25], (const float*)d_in[26],
            (const float*)d_in[27], (const float*)d_in[28],
            nullptr,
            (float*)d_out);
    }
}